// Round 4
// baseline (1466.361 us; speedup 1.0000x reference)
//
#include <hip/hip_runtime.h>
#include <hip/hip_bf16.h>
#include <math.h>

#define DEV_INLINE __device__ __forceinline__

namespace {
constexpr int kB = 32, kD = 512, kH = 32, kW = 32, kN = 1024, kF = 256;
constexpr float kScale = 0.04419417382415922f;   // 1/sqrt(512); S = kScale * <xf_i, xf_j>
constexpr float kLogMarg = -6.931471805599453f;  // -log(1024)
constexpr int TK = 32;
constexpr int LP = TK + 4;  // padded LDS leading dim (float4-aligned: 36*4B=144B)
}

// ---- K0: per-tensor dtype sniff. flags[t]=1 -> fp32, 0 -> bf16. ------------
// (Rounds 1-3 established inputs are fp32; kept as cheap insurance.)
__global__ __launch_bounds__(256) void k_sniff(
    const unsigned short* __restrict__ p0,
    const unsigned short* __restrict__ p1,
    const unsigned short* __restrict__ p2,
    int* __restrict__ flags) {
  const unsigned short* p = (blockIdx.x == 0) ? p0 : (blockIdx.x == 1 ? p1 : p2);
  const int n = (blockIdx.x == 0) ? 65536 : 8192;
  __shared__ int s[256];
  const int t = threadIdx.x;
  int bad = 0;
  for (int k = t; k < n; k += 256)
    if ((p[k] & 0x7F80u) == 0x7F80u) bad++;
  s[t] = bad;
  __syncthreads();
  for (int off = 128; off; off >>= 1) {
    if (t < off) s[t] += s[t + off];
    __syncthreads();
  }
  if (t == 0) flags[blockIdx.x] = (s[0] > 0) ? 1 : 0;
}

DEV_INLINE float ldmix(const void* p, size_t idx, int is_f32) {
  return is_f32 ? ((const float*)p)[idx]
                : __bfloat162float(((const __hip_bfloat16*)p)[idx]);
}

// ---- K1: xf[lb, i, c] = float(x[b0+lb, c, i]) + pos(c, i) ------------------
// pos(c, i): i = h*W + w; c<256 -> col_embed[w][c]; else row_embed[h][c-256]
__global__ __launch_bounds__(256) void k_prep(
    const void* __restrict__ x,
    const void* __restrict__ row_embed,
    const void* __restrict__ col_embed,
    const int* __restrict__ flags,
    float* __restrict__ xf, int b0) {
  const int fx = flags[0], fr = flags[1], fc = flags[2];
  const int bi = blockIdx.x;              // local_b * N + i
  const int i = bi & (kN - 1);
  const int h = i >> 5, w = i & (kW - 1);
  const int c = threadIdx.x;              // 0..255
  const int gb = b0 + (bi >> 10);
  const size_t xb = (size_t)gb * kD * kN + i;
  const float v0 = ldmix(x, xb + (size_t)c * kN, fx) +
                   ldmix(col_embed, (size_t)w * kF + c, fc);
  const float v1 = ldmix(x, xb + (size_t)(c + kF) * kN, fx) +
                   ldmix(row_embed, (size_t)h * kF + c, fr);
  float* dst = xf + (size_t)bi * kD;
  dst[c] = v0;
  dst[c + kF] = v1;
}

// ---- K2: S[lb] = kScale * xf[lb] @ xf[lb]^T  (n x n, k = d = 512) ----------
// 64x64 tile / block of 256 threads, 4x4 per thread, k-tile 32.
__global__ __launch_bounds__(256) void k_gemm_s(
    const float* __restrict__ xf, float* __restrict__ S) {
  __shared__ float As[64][LP];  // [i][k]
  __shared__ float Bs[64][LP];  // [j][k]
  const int b = blockIdx.z;
  const int i0 = blockIdx.y * 64;
  const int j0 = blockIdx.x * 64;
  const float* qb = xf + (size_t)b * kN * kD;
  const int t = threadIdx.x;
  const int tx = t & 15, ty = t >> 4;  // tx -> j, ty -> i
  const int lr = t >> 3;               // 0..31
  const int lk = (t & 7) * 4;          // 0,4,...,28
  float acc[4][4] = {};
  for (int k0 = 0; k0 < kD; k0 += TK) {
    const float4 a0 = *(const float4*)(qb + (size_t)(i0 + lr) * kD + k0 + lk);
    const float4 a1 = *(const float4*)(qb + (size_t)(i0 + lr + 32) * kD + k0 + lk);
    const float4 b0 = *(const float4*)(qb + (size_t)(j0 + lr) * kD + k0 + lk);
    const float4 b1 = *(const float4*)(qb + (size_t)(j0 + lr + 32) * kD + k0 + lk);
    __syncthreads();
    *(float4*)&As[lr][lk] = a0;
    *(float4*)&As[lr + 32][lk] = a1;
    *(float4*)&Bs[lr][lk] = b0;
    *(float4*)&Bs[lr + 32][lk] = b1;
    __syncthreads();
#pragma unroll
    for (int kk = 0; kk < TK; kk += 4) {
      float4 af[4], bf[4];
#pragma unroll
      for (int a = 0; a < 4; a++) af[a] = *(const float4*)&As[ty + 16 * a][kk];
#pragma unroll
      for (int bb = 0; bb < 4; bb++) bf[bb] = *(const float4*)&Bs[tx + 16 * bb][kk];
#pragma unroll
      for (int a = 0; a < 4; a++)
#pragma unroll
        for (int bb = 0; bb < 4; bb++) {
          acc[a][bb] += af[a].x * bf[bb].x;
          acc[a][bb] += af[a].y * bf[bb].y;
          acc[a][bb] += af[a].z * bf[bb].z;
          acc[a][bb] += af[a].w * bf[bb].w;
        }
    }
  }
  float* Sb = S + (size_t)b * kN * kN;
#pragma unroll
  for (int a = 0; a < 4; a++)
#pragma unroll
    for (int bb = 0; bb < 4; bb++)
      Sb[(size_t)(i0 + ty + 16 * a) * kN + j0 + tx + 16 * bb] = acc[a][bb] * kScale;
}

// ---- K3: u[row] = -log(n) - logsumexp_j S[row, j]  (one wave per row) ------
__global__ __launch_bounds__(256) void k_row_lse(
    const float* __restrict__ S, float* __restrict__ u) {
  const int wave = threadIdx.x >> 6;
  const int lane = threadIdx.x & 63;
  const int row = blockIdx.x * 4 + wave;  // over g*N
  const float* Sr = S + (size_t)row * kN;
  float vals[16];
  float m = -INFINITY;
#pragma unroll
  for (int r = 0; r < 4; r++) {
    const float4 v = *(const float4*)(Sr + lane * 4 + r * 256);
    vals[r * 4 + 0] = v.x; vals[r * 4 + 1] = v.y;
    vals[r * 4 + 2] = v.z; vals[r * 4 + 3] = v.w;
    m = fmaxf(m, fmaxf(fmaxf(v.x, v.y), fmaxf(v.z, v.w)));
  }
#pragma unroll
  for (int off = 32; off; off >>= 1) m = fmaxf(m, __shfl_xor(m, off));
  float s = 0.f;
#pragma unroll
  for (int k = 0; k < 16; k++) s += __expf(vals[k] - m);
#pragma unroll
  for (int off = 32; off; off >>= 1) s += __shfl_xor(s, off);
  if (lane == 0) u[row] = kLogMarg - (m + __logf(s));
}

// ---- K4: v[lb,j] = -log(n) - logsumexp_i (S[lb,i,j] + u[lb,i])  (online) ---
__global__ __launch_bounds__(256) void k_col_lse(
    const float* __restrict__ S, const float* __restrict__ u,
    float* __restrict__ v) {
  const int b = blockIdx.y;
  const int j0 = blockIdx.x * 64;
  const int tx = threadIdx.x & 63;
  const int ty = threadIdx.x >> 6;  // 0..3
  const float* Sb = S + (size_t)b * kN * kN;
  const float* ub = u + b * kN;
  float m = -INFINITY, l = 0.f;
  for (int i = ty; i < kN; i += 4) {
    const float s = Sb[(size_t)i * kN + j0 + tx] + ub[i];
    const float mn = fmaxf(m, s);
    l = l * __expf(m - mn) + __expf(s - mn);
    m = mn;
  }
  __shared__ float Ms[4][64], Ls[4][64];
  Ms[ty][tx] = m;
  Ls[ty][tx] = l;
  __syncthreads();
  if (ty == 0) {
#pragma unroll
    for (int r = 1; r < 4; r++) {
      const float m2 = Ms[r][tx], l2 = Ls[r][tx];
      const float mn = fmaxf(m, m2);
      l = l * __expf(m - mn) + l2 * __expf(m2 - mn);
      m = mn;
    }
    v[b * kN + j0 + tx] = kLogMarg - (m + __logf(l));
  }
}

// ---- K5: out[b0+lb, c, i] = sum_j exp(S+u+v) * xf[lb,j,c]  (fp32 out) ------
// 64(i) x 64(c) tile per block; k-loop over j; exp fused into A staging.
__global__ __launch_bounds__(256) void k_out(
    const float* __restrict__ S, const float* __restrict__ xf,
    const float* __restrict__ u, const float* __restrict__ v,
    float* __restrict__ out, int b0) {
  __shared__ float Ps[64][LP];  // [i][j-k]
  __shared__ float Xs[64][LP];  // [c][j-k] (transposed store)
  const int b = blockIdx.z;
  const int i0 = blockIdx.x * 64;
  const int c0 = blockIdx.y * 64;
  const float* Sb = S + (size_t)b * kN * kN;
  const float* xfb = xf + (size_t)b * kN * kD;
  const float* ub = u + b * kN;
  const float* vb = v + b * kN;
  const int t = threadIdx.x;
  const int tx = t & 15, ty = t >> 4;  // tx -> i (coalesced store), ty -> c
  const int lr = t >> 3;               // 0..31
  const int lk = (t & 7) * 4;
  const int jr = t >> 4;               // 0..15
  const int cc = (t & 15) * 4;
  const float u0 = ub[i0 + lr];
  const float u1 = ub[i0 + lr + 32];
  float acc[4][4] = {};
  for (int k0 = 0; k0 < kN; k0 += TK) {
    const float4 s0 = *(const float4*)(Sb + (size_t)(i0 + lr) * kN + k0 + lk);
    const float4 s1 = *(const float4*)(Sb + (size_t)(i0 + lr + 32) * kN + k0 + lk);
    const float4 vv = *(const float4*)(vb + k0 + lk);
    const float4 x0 = *(const float4*)(xfb + (size_t)(k0 + jr) * kD + c0 + cc);
    const float4 x1 = *(const float4*)(xfb + (size_t)(k0 + jr + 16) * kD + c0 + cc);
    __syncthreads();
    float4 p0, p1;
    p0.x = __expf(s0.x + u0 + vv.x); p0.y = __expf(s0.y + u0 + vv.y);
    p0.z = __expf(s0.z + u0 + vv.z); p0.w = __expf(s0.w + u0 + vv.w);
    p1.x = __expf(s1.x + u1 + vv.x); p1.y = __expf(s1.y + u1 + vv.y);
    p1.z = __expf(s1.z + u1 + vv.z); p1.w = __expf(s1.w + u1 + vv.w);
    *(float4*)&Ps[lr][lk] = p0;
    *(float4*)&Ps[lr + 32][lk] = p1;
    Xs[cc + 0][jr] = x0.x; Xs[cc + 1][jr] = x0.y;
    Xs[cc + 2][jr] = x0.z; Xs[cc + 3][jr] = x0.w;
    Xs[cc + 0][jr + 16] = x1.x; Xs[cc + 1][jr + 16] = x1.y;
    Xs[cc + 2][jr + 16] = x1.z; Xs[cc + 3][jr + 16] = x1.w;
    __syncthreads();
#pragma unroll
    for (int kk = 0; kk < TK; kk += 4) {
      float4 af[4], bf[4];
#pragma unroll
      for (int a = 0; a < 4; a++) af[a] = *(const float4*)&Ps[tx + 16 * a][kk];
#pragma unroll
      for (int bb = 0; bb < 4; bb++) bf[bb] = *(const float4*)&Xs[ty + 16 * bb][kk];
#pragma unroll
      for (int a = 0; a < 4; a++)
#pragma unroll
        for (int bb = 0; bb < 4; bb++) {
          acc[a][bb] += af[a].x * bf[bb].x;
          acc[a][bb] += af[a].y * bf[bb].y;
          acc[a][bb] += af[a].z * bf[bb].z;
          acc[a][bb] += af[a].w * bf[bb].w;
        }
    }
  }
#pragma unroll
  for (int a = 0; a < 4; a++)
#pragma unroll
    for (int bb = 0; bb < 4; bb++) {
      const int i = i0 + tx + 16 * a;
      const int c = c0 + ty + 16 * bb;
      out[((size_t)(b0 + b) * kD + c) * kN + i] = acc[a][bb];
    }
}

extern "C" void kernel_launch(void* const* d_in, const int* in_sizes, int n_in,
                              void* d_out, int out_size, void* d_ws, size_t ws_size,
                              hipStream_t stream) {
  float* out = (float*)d_out;  // fp32 output (inputs proven fp32 -> fp32 ref)

  // ws layout: [256B header: 3 dtype flags][xf: G*N*D f32][S: G*N*N f32][u,v].
  // Per-batch need = (N*D + N*N + 2*N)*4 B ~= 6.008 MB. Chunk batches to fit.
  char* wsb = (char*)d_ws;
  int* flags = (int*)wsb;
  float* base = (float*)(wsb + 256);
  const size_t per_b = (size_t)kN * kD + (size_t)kN * kN + 2 * kN;  // floats
  const size_t avail = (ws_size > 256) ? (ws_size - 256) / 4 : 0;   // floats
  int G = (int)(avail / per_b);
  if (G > kB) G = kB;
  if (G < 1) G = 1;  // (ws_size < 6 MB would be unusable anyway)
  float* xf = base;
  float* S = xf + (size_t)G * kN * kD;
  float* u = S + (size_t)G * kN * kN;
  float* v = u + (size_t)G * kN;

  k_sniff<<<3, 256, 0, stream>>>((const unsigned short*)d_in[0],
                                 (const unsigned short*)d_in[1],
                                 (const unsigned short*)d_in[2], flags);

  for (int b0 = 0; b0 < kB; b0 += G) {
    const int g = (kB - b0 < G) ? (kB - b0) : G;
    k_prep<<<g * kN, 256, 0, stream>>>(d_in[0], d_in[1], d_in[2], flags, xf, b0);
    k_gemm_s<<<dim3(kN / 64, kN / 64, g), 256, 0, stream>>>(xf, S);
    k_row_lse<<<g * kN / 4, 256, 0, stream>>>(S, u);
    k_col_lse<<<dim3(kN / 64, g), 256, 0, stream>>>(S, u, v);
    k_out<<<dim3(kN / 64, kD / 64, g), 256, 0, stream>>>(S, xf, u, v, out, b0);
  }
}

// Round 5
// 472.868 us; speedup vs baseline: 3.1010x; 3.1010x over previous
//
#include <hip/hip_runtime.h>
#include <hip/hip_fp16.h>
#include <math.h>

typedef _Float16 f16;
typedef _Float16 f16x8 __attribute__((ext_vector_type(8)));
typedef _Float16 f16x4 __attribute__((ext_vector_type(4)));
typedef float f32x4 __attribute__((ext_vector_type(4)));

namespace {
constexpr int kB = 32, kD = 512, kN = 1024, kF = 256;
constexpr float kScale = 0.04419417382415922f;   // 1/sqrt(512)
constexpr float kLogMarg = -6.931471805599453f;  // -log(1024)
constexpr float kPScale = 16384.f;               // 2^14: lift P into fp16 normal range
constexpr float kPInv = 1.f / 16384.f;
constexpr int LDK = 72;  // padded LDS row: 72 f16 = 144 B (16B-aligned, 2-way banks)
}

// ---- K1: val = x[b,c,i] + pos(c,i); emit xfT[lb,c,i] and xf[lb,i,c] (f16) --
// 64x64 (c x i) tile; x read coalesced along i; LDS transpose for xf.
__global__ __launch_bounds__(256) void k_prep(
    const float* __restrict__ x, const float* __restrict__ re,
    const float* __restrict__ ce, f16* __restrict__ xf,
    f16* __restrict__ xfT, int b0) {
  __shared__ f16 T[64][68];
  const int lb = blockIdx.z;
  const int i0 = blockIdx.x * 64, c0 = blockIdx.y * 64;
  const int t = threadIdx.x;
  const int il = (t & 15) * 4;  // 0..60
  const int cl = t >> 4;        // 0..15
  const size_t xbase = ((size_t)(b0 + lb) * kD) * kN;
#pragma unroll
  for (int p = 0; p < 4; p++) {
    const int c = c0 + cl + 16 * p;
    const int i = i0 + il;
    const float4 xv = *(const float4*)(x + xbase + (size_t)c * kN + i);
    float4 pv;
    if (c < kF) {  // wave-uniform per block (c0 multiple of 64)
      pv.x = ce[((i + 0) & 31) * kF + c];
      pv.y = ce[((i + 1) & 31) * kF + c];
      pv.z = ce[((i + 2) & 31) * kF + c];
      pv.w = ce[((i + 3) & 31) * kF + c];
    } else {
      const float r = re[(i >> 5) * kF + (c - kF)];
      pv.x = r; pv.y = r; pv.z = r; pv.w = r;
    }
    const f16 h0 = (f16)(xv.x + pv.x), h1 = (f16)(xv.y + pv.y);
    const f16 h2 = (f16)(xv.z + pv.z), h3 = (f16)(xv.w + pv.w);
    f16* dT = xfT + ((size_t)lb * kD + c) * kN + i;
    *(f16x4*)dT = (f16x4){h0, h1, h2, h3};
    T[cl + 16 * p][il + 0] = h0; T[cl + 16 * p][il + 1] = h1;
    T[cl + 16 * p][il + 2] = h2; T[cl + 16 * p][il + 3] = h3;
  }
  __syncthreads();
#pragma unroll
  for (int p = 0; p < 4; p++) {
    const int ir = cl + 16 * p;  // local i
    const int cc = il;           // local c
    const f16 h0 = T[cc + 0][ir], h1 = T[cc + 1][ir];
    const f16 h2 = T[cc + 2][ir], h3 = T[cc + 3][ir];
    f16* dF = xf + ((size_t)lb * kN + i0 + ir) * kD + c0 + cc;
    *(f16x4*)dF = (f16x4){h0, h1, h2, h3};
  }
}

// ---- K2: S[lb] = kScale * xf @ xf^T via fp16 MFMA. 128x128 tile, BK=64. ----
__global__ __launch_bounds__(256) void k_gemm_s(
    const f16* __restrict__ xf, float* __restrict__ S) {
  __shared__ f16 As[128][LDK];
  __shared__ f16 Bs[128][LDK];
  const int lb = blockIdx.z;
  const int i0 = blockIdx.y * 128, j0 = blockIdx.x * 128;
  const f16* base = xf + (size_t)lb * kN * kD;
  const int t = threadIdx.x;
  const int w = t >> 6, lane = t & 63;
  const int m_off = (w >> 1) * 64, n_off = (w & 1) * 64;
  const int quad = lane >> 4, l15 = lane & 15;
  const int sc = (t & 7) * 8;  // staging col (8 f16 = 16 B)
  const int sr = t >> 3;       // staging row 0..31
  f32x4 acc[4][4];
#pragma unroll
  for (int a = 0; a < 4; a++)
#pragma unroll
    for (int b = 0; b < 4; b++) acc[a][b] = (f32x4){0.f, 0.f, 0.f, 0.f};

  for (int k0 = 0; k0 < kD; k0 += 64) {
    f16x8 a[4], b[4];
#pragma unroll
    for (int p = 0; p < 4; p++) {
      a[p] = *(const f16x8*)(base + (size_t)(i0 + sr + 32 * p) * kD + k0 + sc);
      b[p] = *(const f16x8*)(base + (size_t)(j0 + sr + 32 * p) * kD + k0 + sc);
    }
    __syncthreads();
#pragma unroll
    for (int p = 0; p < 4; p++) {
      *(f16x8*)&As[sr + 32 * p][sc] = a[p];
      *(f16x8*)&Bs[sr + 32 * p][sc] = b[p];
    }
    __syncthreads();
#pragma unroll
    for (int kk = 0; kk < 64; kk += 32) {
      f16x8 af[4], bf[4];
#pragma unroll
      for (int q = 0; q < 4; q++)
        af[q] = *(const f16x8*)&As[m_off + 16 * q + l15][kk + quad * 8];
#pragma unroll
      for (int q = 0; q < 4; q++)
        bf[q] = *(const f16x8*)&Bs[n_off + 16 * q + l15][kk + quad * 8];
#pragma unroll
      for (int qa = 0; qa < 4; qa++)
#pragma unroll
        for (int qb = 0; qb < 4; qb++)
          acc[qa][qb] = __builtin_amdgcn_mfma_f32_16x16x32_f16(
              af[qa], bf[qb], acc[qa][qb], 0, 0, 0);
    }
  }
  float* Sb = S + (size_t)lb * kN * kN;
#pragma unroll
  for (int qa = 0; qa < 4; qa++) {
    const int i = i0 + m_off + 16 * qa + quad * 4;
#pragma unroll
    for (int qb = 0; qb < 4; qb++) {
      const int j = j0 + n_off + 16 * qb + l15;
#pragma unroll
      for (int r = 0; r < 4; r++)
        Sb[(size_t)(i + r) * kN + j] = acc[qa][qb][r] * kScale;
    }
  }
}

// ---- K3: u[row] = -log(n) - logsumexp_j S[row,j] (one wave per row) --------
__global__ __launch_bounds__(256) void k_row_lse(
    const float* __restrict__ S, float* __restrict__ u) {
  const int wave = threadIdx.x >> 6;
  const int lane = threadIdx.x & 63;
  const int row = blockIdx.x * 4 + wave;
  const float* Sr = S + (size_t)row * kN;
  float vals[16];
  float m = -INFINITY;
#pragma unroll
  for (int r = 0; r < 4; r++) {
    const float4 v = *(const float4*)(Sr + lane * 4 + r * 256);
    vals[r * 4 + 0] = v.x; vals[r * 4 + 1] = v.y;
    vals[r * 4 + 2] = v.z; vals[r * 4 + 3] = v.w;
    m = fmaxf(m, fmaxf(fmaxf(v.x, v.y), fmaxf(v.z, v.w)));
  }
#pragma unroll
  for (int off = 32; off; off >>= 1) m = fmaxf(m, __shfl_xor(m, off));
  float s = 0.f;
#pragma unroll
  for (int k = 0; k < 16; k++) s += __expf(vals[k] - m);
#pragma unroll
  for (int off = 32; off; off >>= 1) s += __shfl_xor(s, off);
  if (lane == 0) u[row] = kLogMarg - (m + __logf(s));
}

// ---- K4: v[lb,j] = -log(n) - logsumexp_i (S[lb,i,j] + u[lb,i]) -------------
__global__ __launch_bounds__(256) void k_col_lse(
    const float* __restrict__ S, const float* __restrict__ u,
    float* __restrict__ v) {
  const int b = blockIdx.y;
  const int j0 = blockIdx.x * 64;
  const int tx = threadIdx.x & 63;
  const int ty = threadIdx.x >> 6;
  const float* Sb = S + (size_t)b * kN * kN;
  const float* ub = u + b * kN;
  float m = -INFINITY, l = 0.f;
  for (int i = ty; i < kN; i += 4) {
    const float s = Sb[(size_t)i * kN + j0 + tx] + ub[i];
    const float mn = fmaxf(m, s);
    l = l * __expf(m - mn) + __expf(s - mn);
    m = mn;
  }
  __shared__ float Ms[4][64], Ls[4][64];
  Ms[ty][tx] = m;
  Ls[ty][tx] = l;
  __syncthreads();
  if (ty == 0) {
#pragma unroll
    for (int r = 1; r < 4; r++) {
      const float m2 = Ms[r][tx], l2 = Ls[r][tx];
      const float mn = fmaxf(m, m2);
      l = l * __expf(m - mn) + l2 * __expf(m2 - mn);
      m = mn;
    }
    v[b * kN + j0 + tx] = kLogMarg - (m + __logf(l));
  }
}

// ---- K5: P16[row,j] = fp16(2^14 * exp(S + u_i + v_j)) ----------------------
__global__ __launch_bounds__(256) void k_pexp(
    const float* __restrict__ S, const float* __restrict__ u,
    const float* __restrict__ v, f16* __restrict__ P) {
  const int row = blockIdx.x;  // lb*kN + i
  const float ui = u[row];
  const float* Sr = S + (size_t)row * kN;
  const float* vb = v + (size_t)(row >> 10) * kN;
  f16* Pr = P + (size_t)row * kN;
  const int j = threadIdx.x * 4;
  const float4 s = *(const float4*)(Sr + j);
  const float4 vv = *(const float4*)(vb + j);
  f16x4 o;
  o[0] = (f16)(__expf(s.x + ui + vv.x) * kPScale);
  o[1] = (f16)(__expf(s.y + ui + vv.y) * kPScale);
  o[2] = (f16)(__expf(s.z + ui + vv.z) * kPScale);
  o[3] = (f16)(__expf(s.w + ui + vv.w) * kPScale);
  *(f16x4*)(Pr + j) = o;
}

// ---- K6: out[b,c,i] = (1/2^14) * sum_j xfT[c,j] * P[i,j]  (fp16 MFMA) ------
// D[m=c][n=i]; A = xfT rows (k=j contig), B = P rows (k=j contig). K=1024.
__global__ __launch_bounds__(256) void k_gemm_o(
    const f16* __restrict__ xfT, const f16* __restrict__ P,
    float* __restrict__ out, int b0) {
  __shared__ f16 As[128][LDK];
  __shared__ f16 Bs[128][LDK];
  const int lb = blockIdx.z;
  const int i0 = blockIdx.x * 128, c0 = blockIdx.y * 128;
  const f16* Ab = xfT + (size_t)lb * kD * kN;
  const f16* Bb = P + (size_t)lb * kN * kN;
  const int t = threadIdx.x;
  const int w = t >> 6, lane = t & 63;
  const int m_off = (w >> 1) * 64, n_off = (w & 1) * 64;
  const int quad = lane >> 4, l15 = lane & 15;
  const int sc = (t & 7) * 8;
  const int sr = t >> 3;
  f32x4 acc[4][4];
#pragma unroll
  for (int a = 0; a < 4; a++)
#pragma unroll
    for (int b = 0; b < 4; b++) acc[a][b] = (f32x4){0.f, 0.f, 0.f, 0.f};

  for (int k0 = 0; k0 < kN; k0 += 64) {
    f16x8 a[4], b[4];
#pragma unroll
    for (int p = 0; p < 4; p++) {
      a[p] = *(const f16x8*)(Ab + (size_t)(c0 + sr + 32 * p) * kN + k0 + sc);
      b[p] = *(const f16x8*)(Bb + (size_t)(i0 + sr + 32 * p) * kN + k0 + sc);
    }
    __syncthreads();
#pragma unroll
    for (int p = 0; p < 4; p++) {
      *(f16x8*)&As[sr + 32 * p][sc] = a[p];
      *(f16x8*)&Bs[sr + 32 * p][sc] = b[p];
    }
    __syncthreads();
#pragma unroll
    for (int kk = 0; kk < 64; kk += 32) {
      f16x8 af[4], bf[4];
#pragma unroll
      for (int q = 0; q < 4; q++)
        af[q] = *(const f16x8*)&As[m_off + 16 * q + l15][kk + quad * 8];
#pragma unroll
      for (int q = 0; q < 4; q++)
        bf[q] = *(const f16x8*)&Bs[n_off + 16 * q + l15][kk + quad * 8];
#pragma unroll
      for (int qa = 0; qa < 4; qa++)
#pragma unroll
        for (int qb = 0; qb < 4; qb++)
          acc[qa][qb] = __builtin_amdgcn_mfma_f32_16x16x32_f16(
              af[qa], bf[qb], acc[qa][qb], 0, 0, 0);
    }
  }
  float* ob = out + ((size_t)(b0 + lb) * kD) * kN;
#pragma unroll
  for (int qa = 0; qa < 4; qa++) {
    const int c = c0 + m_off + 16 * qa + quad * 4;
#pragma unroll
    for (int qb = 0; qb < 4; qb++) {
      const int i = i0 + n_off + 16 * qb + l15;
#pragma unroll
      for (int r = 0; r < 4; r++)
        ob[(size_t)(c + r) * kN + i] = acc[qa][qb][r] * kPInv;
    }
  }
}

extern "C" void kernel_launch(void* const* d_in, const int* in_sizes, int n_in,
                              void* d_out, int out_size, void* d_ws, size_t ws_size,
                              hipStream_t stream) {
  const float* x = (const float*)d_in[0];
  const float* re = (const float*)d_in[1];
  const float* ce = (const float*)d_in[2];
  float* out = (float*)d_out;

  // ws per batch: S 4MB (f32) + xf 1MB + xfT 1MB + P 2MB (f16) + u,v 8KB.
  char* wsb = (char*)d_ws;
  const size_t perb = 4194304 + 1048576 + 1048576 + 2097152 + 8192;
  int G = (int)(ws_size / perb);
  if (G >= 32) G = 32;
  else if (G >= 16) G = 16;
  else if (G >= 8) G = 8;
  else if (G >= 4) G = 4;
  else if (G < 1) G = 1;
  float* S = (float*)wsb;
  f16* xf = (f16*)(wsb + (size_t)G * 4194304);
  f16* xfT = (f16*)((char*)xf + (size_t)G * 1048576);
  f16* P = (f16*)((char*)xfT + (size_t)G * 1048576);
  float* u = (float*)((char*)P + (size_t)G * 2097152);
  float* v = u + (size_t)G * kN;

  for (int b0 = 0; b0 < kB; b0 += G) {
    const int g = (kB - b0 < G) ? (kB - b0) : G;
    k_prep<<<dim3(16, 8, g), 256, 0, stream>>>(x, re, ce, xf, xfT, b0);
    k_gemm_s<<<dim3(8, 8, g), 256, 0, stream>>>(xf, S);
    k_row_lse<<<g * kN / 4, 256, 0, stream>>>(S, u);
    k_col_lse<<<dim3(16, g), 256, 0, stream>>>(S, u, v);
    k_pexp<<<g * kN, 256, 0, stream>>>(S, u, v, P);
    k_gemm_o<<<dim3(8, 4, g), 256, 0, stream>>>(xfT, P, out, b0);
  }
}

// Round 6
// 331.979 us; speedup vs baseline: 4.4170x; 1.4244x over previous
//
#include <hip/hip_runtime.h>
#include <hip/hip_fp16.h>
#include <math.h>

typedef _Float16 f16;
typedef _Float16 f16x8 __attribute__((ext_vector_type(8)));
typedef _Float16 f16x4 __attribute__((ext_vector_type(4)));
typedef float f32x4 __attribute__((ext_vector_type(4)));

namespace {
constexpr int kB = 32, kD = 512, kN = 1024, kF = 256;
constexpr float kScale = 0.04419417382415922f;   // 1/sqrt(512)
constexpr float kLogMarg = -6.931471805599453f;  // -log(1024)
constexpr float kPScale = 16384.f;               // 2^14: lift P into fp16 normal range
constexpr float kPInv = 1.f / 16384.f;
constexpr int LDK = 72;  // padded LDS row: 72 f16 = 144 B (16B-aligned, 2-way banks)
}

// ---- K1: val = x[b,c,i] + pos(c,i); emit xfT[lb,c,i] and xf[lb,i,c] (f16) --
__global__ __launch_bounds__(256) void k_prep(
    const float* __restrict__ x, const float* __restrict__ re,
    const float* __restrict__ ce, f16* __restrict__ xf,
    f16* __restrict__ xfT, int b0) {
  __shared__ f16 T[64][68];
  const int lb = blockIdx.z;
  const int i0 = blockIdx.x * 64, c0 = blockIdx.y * 64;
  const int t = threadIdx.x;
  const int il = (t & 15) * 4;  // 0..60
  const int cl = t >> 4;        // 0..15
  const size_t xbase = ((size_t)(b0 + lb) * kD) * kN;
#pragma unroll
  for (int p = 0; p < 4; p++) {
    const int c = c0 + cl + 16 * p;
    const int i = i0 + il;
    const float4 xv = *(const float4*)(x + xbase + (size_t)c * kN + i);
    float4 pv;
    if (c < kF) {  // wave-uniform per block (c0 multiple of 64)
      pv.x = ce[((i + 0) & 31) * kF + c];
      pv.y = ce[((i + 1) & 31) * kF + c];
      pv.z = ce[((i + 2) & 31) * kF + c];
      pv.w = ce[((i + 3) & 31) * kF + c];
    } else {
      const float r = re[(i >> 5) * kF + (c - kF)];
      pv.x = r; pv.y = r; pv.z = r; pv.w = r;
    }
    const f16 h0 = (f16)(xv.x + pv.x), h1 = (f16)(xv.y + pv.y);
    const f16 h2 = (f16)(xv.z + pv.z), h3 = (f16)(xv.w + pv.w);
    f16* dT = xfT + ((size_t)lb * kD + c) * kN + i;
    *(f16x4*)dT = (f16x4){h0, h1, h2, h3};
    T[cl + 16 * p][il + 0] = h0; T[cl + 16 * p][il + 1] = h1;
    T[cl + 16 * p][il + 2] = h2; T[cl + 16 * p][il + 3] = h3;
  }
  __syncthreads();
#pragma unroll
  for (int p = 0; p < 4; p++) {
    const int ir = cl + 16 * p;  // local i
    const int cc = il;           // local c
    const f16 h0 = T[cc + 0][ir], h1 = T[cc + 1][ir];
    const f16 h2 = T[cc + 2][ir], h3 = T[cc + 3][ir];
    f16* dF = xf + ((size_t)lb * kN + i0 + ir) * kD + c0 + cc;
    *(f16x4*)dF = (f16x4){h0, h1, h2, h3};
  }
}

// ---- K2: S[lb] = kScale * xf @ xf^T via fp16 MFMA. 128x128 tile, BK=64. ----
__global__ __launch_bounds__(256) void k_gemm_s(
    const f16* __restrict__ xf, float* __restrict__ S) {
  __shared__ f16 As[128][LDK];
  __shared__ f16 Bs[128][LDK];
  const int lb = blockIdx.z;
  const int i0 = blockIdx.y * 128, j0 = blockIdx.x * 128;
  const f16* base = xf + (size_t)lb * kN * kD;
  const int t = threadIdx.x;
  const int w = t >> 6, lane = t & 63;
  const int m_off = (w >> 1) * 64, n_off = (w & 1) * 64;
  const int quad = lane >> 4, l15 = lane & 15;
  const int sc = (t & 7) * 8;  // staging col (8 f16 = 16 B)
  const int sr = t >> 3;       // staging row 0..31
  f32x4 acc[4][4];
#pragma unroll
  for (int a = 0; a < 4; a++)
#pragma unroll
    for (int b = 0; b < 4; b++) acc[a][b] = (f32x4){0.f, 0.f, 0.f, 0.f};

  for (int k0 = 0; k0 < kD; k0 += 64) {
    f16x8 a[4], b[4];
#pragma unroll
    for (int p = 0; p < 4; p++) {
      a[p] = *(const f16x8*)(base + (size_t)(i0 + sr + 32 * p) * kD + k0 + sc);
      b[p] = *(const f16x8*)(base + (size_t)(j0 + sr + 32 * p) * kD + k0 + sc);
    }
    __syncthreads();
#pragma unroll
    for (int p = 0; p < 4; p++) {
      *(f16x8*)&As[sr + 32 * p][sc] = a[p];
      *(f16x8*)&Bs[sr + 32 * p][sc] = b[p];
    }
    __syncthreads();
#pragma unroll
    for (int kk = 0; kk < 64; kk += 32) {
      f16x8 af[4], bf[4];
#pragma unroll
      for (int q = 0; q < 4; q++)
        af[q] = *(const f16x8*)&As[m_off + 16 * q + l15][kk + quad * 8];
#pragma unroll
      for (int q = 0; q < 4; q++)
        bf[q] = *(const f16x8*)&Bs[n_off + 16 * q + l15][kk + quad * 8];
#pragma unroll
      for (int qa = 0; qa < 4; qa++)
#pragma unroll
        for (int qb = 0; qb < 4; qb++)
          acc[qa][qb] = __builtin_amdgcn_mfma_f32_16x16x32_f16(
              af[qa], bf[qb], acc[qa][qb], 0, 0, 0);
    }
  }
  float* Sb = S + (size_t)lb * kN * kN;
#pragma unroll
  for (int qa = 0; qa < 4; qa++) {
    const int i = i0 + m_off + 16 * qa + quad * 4;
#pragma unroll
    for (int qb = 0; qb < 4; qb++) {
      const int j = j0 + n_off + 16 * qb + l15;
#pragma unroll
      for (int r = 0; r < 4; r++)
        Sb[(size_t)(i + r) * kN + j] = acc[qa][qb][r] * kScale;
    }
  }
}

// ---- K3: u[row] = -log(n) - logsumexp_j S[row,j] (one wave per row) --------
__global__ __launch_bounds__(256) void k_row_lse(
    const float* __restrict__ S, float* __restrict__ u) {
  const int wave = threadIdx.x >> 6;
  const int lane = threadIdx.x & 63;
  const int row = blockIdx.x * 4 + wave;
  const float* Sr = S + (size_t)row * kN;
  float vals[16];
  float m = -INFINITY;
#pragma unroll
  for (int r = 0; r < 4; r++) {
    const float4 v = *(const float4*)(Sr + lane * 4 + r * 256);
    vals[r * 4 + 0] = v.x; vals[r * 4 + 1] = v.y;
    vals[r * 4 + 2] = v.z; vals[r * 4 + 3] = v.w;
    m = fmaxf(m, fmaxf(fmaxf(v.x, v.y), fmaxf(v.z, v.w)));
  }
#pragma unroll
  for (int off = 32; off; off >>= 1) m = fmaxf(m, __shfl_xor(m, off));
  float s = 0.f;
#pragma unroll
  for (int k = 0; k < 16; k++) s += __expf(vals[k] - m);
#pragma unroll
  for (int off = 32; off; off >>= 1) s += __shfl_xor(s, off);
  if (lane == 0) u[row] = kLogMarg - (m + __logf(s));
}

// ---- K4a: column partial sums of exp(S + u_i), 64x64 tile per block. -------
// No max needed: S_ij + u_i <= -log(n), so terms <= 1/1024; each column holds
// its diagonal term ~1/n, so sums stay well inside fp32 range.
__global__ __launch_bounds__(256) void k_colsum(
    const float* __restrict__ S, const float* __restrict__ u,
    float* __restrict__ cp) {
  const int lb = blockIdx.z;
  const int seg = blockIdx.y;       // 0..15: i-range [seg*64, seg*64+64)
  const int j0 = blockIdx.x * 64;
  const int tx = threadIdx.x & 63;  // column
  const int ty = threadIdx.x >> 6;  // row group (wave per group: coalesced)
  const float* Sb = S + (size_t)lb * kN * kN;
  const float* ub = u + lb * kN;
  const int ibase = seg * 64 + ty * 16;
  float s = 0.f;
#pragma unroll 4
  for (int r = 0; r < 16; r++) {
    const int i = ibase + r;
    s += __expf(Sb[(size_t)i * kN + j0 + tx] + ub[i]);
  }
  __shared__ float Ss[4][64];
  Ss[ty][tx] = s;
  __syncthreads();
  if (ty == 0) {
    s += Ss[1][tx] + Ss[2][tx] + Ss[3][tx];
    cp[((size_t)lb * 16 + seg) * kN + j0 + tx] = s;
  }
}

// ---- K4b: v[lb,j] = -log(n) - log(sum of 16 partials) ----------------------
__global__ __launch_bounds__(256) void k_vfin(
    const float* __restrict__ cp, float* __restrict__ v) {
  const int lb = blockIdx.y;
  const int j = blockIdx.x * 256 + threadIdx.x;
  const float* c = cp + (size_t)lb * 16 * kN + j;
  float s = 0.f;
#pragma unroll
  for (int r = 0; r < 16; r++) s += c[(size_t)r * kN];
  v[lb * kN + j] = kLogMarg - __logf(s);
}

// ---- K5: P16[row,j] = fp16(2^14 * exp(S + u_i + v_j)) ----------------------
__global__ __launch_bounds__(256) void k_pexp(
    const float* __restrict__ S, const float* __restrict__ u,
    const float* __restrict__ v, f16* __restrict__ P) {
  const int row = blockIdx.x;  // lb*kN + i
  const float ui = u[row];
  const float* Sr = S + (size_t)row * kN;
  const float* vb = v + (size_t)(row >> 10) * kN;
  f16* Pr = P + (size_t)row * kN;
  const int j = threadIdx.x * 4;
  const float4 s = *(const float4*)(Sr + j);
  const float4 vv = *(const float4*)(vb + j);
  f16x4 o;
  o[0] = (f16)(__expf(s.x + ui + vv.x) * kPScale);
  o[1] = (f16)(__expf(s.y + ui + vv.y) * kPScale);
  o[2] = (f16)(__expf(s.z + ui + vv.z) * kPScale);
  o[3] = (f16)(__expf(s.w + ui + vv.w) * kPScale);
  *(f16x4*)(Pr + j) = o;
}

// ---- K6: out[b,c,i] = (1/2^14) * sum_j xfT[c,j] * P[i,j]  (fp16 MFMA) ------
__global__ __launch_bounds__(256) void k_gemm_o(
    const f16* __restrict__ xfT, const f16* __restrict__ P,
    float* __restrict__ out, int b0) {
  __shared__ f16 As[128][LDK];
  __shared__ f16 Bs[128][LDK];
  const int lb = blockIdx.z;
  const int i0 = blockIdx.x * 128, c0 = blockIdx.y * 128;
  const f16* Ab = xfT + (size_t)lb * kD * kN;
  const f16* Bb = P + (size_t)lb * kN * kN;
  const int t = threadIdx.x;
  const int w = t >> 6, lane = t & 63;
  const int m_off = (w >> 1) * 64, n_off = (w & 1) * 64;
  const int quad = lane >> 4, l15 = lane & 15;
  const int sc = (t & 7) * 8;
  const int sr = t >> 3;
  f32x4 acc[4][4];
#pragma unroll
  for (int a = 0; a < 4; a++)
#pragma unroll
    for (int b = 0; b < 4; b++) acc[a][b] = (f32x4){0.f, 0.f, 0.f, 0.f};

  for (int k0 = 0; k0 < kN; k0 += 64) {
    f16x8 a[4], b[4];
#pragma unroll
    for (int p = 0; p < 4; p++) {
      a[p] = *(const f16x8*)(Ab + (size_t)(c0 + sr + 32 * p) * kN + k0 + sc);
      b[p] = *(const f16x8*)(Bb + (size_t)(i0 + sr + 32 * p) * kN + k0 + sc);
    }
    __syncthreads();
#pragma unroll
    for (int p = 0; p < 4; p++) {
      *(f16x8*)&As[sr + 32 * p][sc] = a[p];
      *(f16x8*)&Bs[sr + 32 * p][sc] = b[p];
    }
    __syncthreads();
#pragma unroll
    for (int kk = 0; kk < 64; kk += 32) {
      f16x8 af[4], bf[4];
#pragma unroll
      for (int q = 0; q < 4; q++)
        af[q] = *(const f16x8*)&As[m_off + 16 * q + l15][kk + quad * 8];
#pragma unroll
      for (int q = 0; q < 4; q++)
        bf[q] = *(const f16x8*)&Bs[n_off + 16 * q + l15][kk + quad * 8];
#pragma unroll
      for (int qa = 0; qa < 4; qa++)
#pragma unroll
        for (int qb = 0; qb < 4; qb++)
          acc[qa][qb] = __builtin_amdgcn_mfma_f32_16x16x32_f16(
              af[qa], bf[qb], acc[qa][qb], 0, 0, 0);
    }
  }
  float* ob = out + ((size_t)(b0 + lb) * kD) * kN;
#pragma unroll
  for (int qa = 0; qa < 4; qa++) {
    const int c = c0 + m_off + 16 * qa + quad * 4;
#pragma unroll
    for (int qb = 0; qb < 4; qb++) {
      const int i = i0 + n_off + 16 * qb + l15;
#pragma unroll
      for (int r = 0; r < 4; r++)
        ob[(size_t)(c + r) * kN + i] = acc[qa][qb][r] * kPInv;
    }
  }
}

extern "C" void kernel_launch(void* const* d_in, const int* in_sizes, int n_in,
                              void* d_out, int out_size, void* d_ws, size_t ws_size,
                              hipStream_t stream) {
  const float* x = (const float*)d_in[0];
  const float* re = (const float*)d_in[1];
  const float* ce = (const float*)d_in[2];
  float* out = (float*)d_out;

  // ws per batch: S 4MB (f32) + xf 1MB + xfT 1MB + P 2MB (f16) + u,v 8KB
  //             + colsum partials 16*kN f32 = 64KB.
  char* wsb = (char*)d_ws;
  const size_t perb = 4194304 + 1048576 + 1048576 + 2097152 + 8192 + 65536;
  int G = (int)(ws_size / perb);
  if (G >= 32) G = 32;
  else if (G >= 16) G = 16;
  else if (G >= 8) G = 8;
  else if (G >= 4) G = 4;
  else if (G < 1) G = 1;
  float* S = (float*)wsb;
  f16* xf = (f16*)(wsb + (size_t)G * 4194304);
  f16* xfT = (f16*)((char*)xf + (size_t)G * 1048576);
  f16* P = (f16*)((char*)xfT + (size_t)G * 1048576);
  float* u = (float*)((char*)P + (size_t)G * 2097152);
  float* v = u + (size_t)G * kN;
  float* cp = v + (size_t)G * kN;  // [G][16][kN] column partials

  for (int b0 = 0; b0 < kB; b0 += G) {
    const int g = (kB - b0 < G) ? (kB - b0) : G;
    k_prep<<<dim3(16, 8, g), 256, 0, stream>>>(x, re, ce, xf, xfT, b0);
    k_gemm_s<<<dim3(8, 8, g), 256, 0, stream>>>(xf, S);
    k_row_lse<<<g * kN / 4, 256, 0, stream>>>(S, u);
    k_colsum<<<dim3(16, 16, g), 256, 0, stream>>>(S, u, cp);
    k_vfin<<<dim3(4, g), 256, 0, stream>>>(cp, v);
    k_pexp<<<g * kN, 256, 0, stream>>>(S, u, v, P);
    k_gemm_o<<<dim3(8, 4, g), 256, 0, stream>>>(xfT, P, out, b0);
  }
}

// Round 7
// 310.714 us; speedup vs baseline: 4.7193x; 1.0684x over previous
//
#include <hip/hip_runtime.h>
#include <hip/hip_fp16.h>
#include <math.h>

typedef _Float16 f16;
typedef _Float16 f16x8 __attribute__((ext_vector_type(8)));
typedef _Float16 f16x4 __attribute__((ext_vector_type(4)));
typedef float f32x4 __attribute__((ext_vector_type(4)));

namespace {
constexpr int kB = 32, kD = 512, kN = 1024, kF = 256;
constexpr float kScale = 0.04419417382415922f;   // 1/sqrt(512)
constexpr float kLogMarg = -6.931471805599453f;  // -log(1024)
constexpr float kMarg = 1.f / 1024.f;            // 1/n
constexpr float kPScale = 16384.f;               // 2^14: lift t into f16 range
constexpr float kPInv = 1.f / 16384.f;
constexpr int LDK = 72;  // padded LDS row: 72 f16 = 144 B (16B-aligned, 2-way banks)
}

// ---- K1: val = x[b,c,i] + pos(c,i); emit xfT[lb,c,i] and xf[lb,i,c] (f16) --
__global__ __launch_bounds__(256) void k_prep(
    const float* __restrict__ x, const float* __restrict__ re,
    const float* __restrict__ ce, f16* __restrict__ xf,
    f16* __restrict__ xfT, int b0) {
  __shared__ f16 T[64][68];
  const int lb = blockIdx.z;
  const int i0 = blockIdx.x * 64, c0 = blockIdx.y * 64;
  const int t = threadIdx.x;
  const int il = (t & 15) * 4;  // 0..60
  const int cl = t >> 4;        // 0..15
  const size_t xbase = ((size_t)(b0 + lb) * kD) * kN;
#pragma unroll
  for (int p = 0; p < 4; p++) {
    const int c = c0 + cl + 16 * p;
    const int i = i0 + il;
    const float4 xv = *(const float4*)(x + xbase + (size_t)c * kN + i);
    float4 pv;
    if (c < kF) {  // wave-uniform per block (c0 multiple of 64)
      pv.x = ce[((i + 0) & 31) * kF + c];
      pv.y = ce[((i + 1) & 31) * kF + c];
      pv.z = ce[((i + 2) & 31) * kF + c];
      pv.w = ce[((i + 3) & 31) * kF + c];
    } else {
      const float r = re[(i >> 5) * kF + (c - kF)];
      pv.x = r; pv.y = r; pv.z = r; pv.w = r;
    }
    const f16 h0 = (f16)(xv.x + pv.x), h1 = (f16)(xv.y + pv.y);
    const f16 h2 = (f16)(xv.z + pv.z), h3 = (f16)(xv.w + pv.w);
    f16* dT = xfT + ((size_t)lb * kD + c) * kN + i;
    *(f16x4*)dT = (f16x4){h0, h1, h2, h3};
    T[cl + 16 * p][il + 0] = h0; T[cl + 16 * p][il + 1] = h1;
    T[cl + 16 * p][il + 2] = h2; T[cl + 16 * p][il + 3] = h3;
  }
  __syncthreads();
#pragma unroll
  for (int p = 0; p < 4; p++) {
    const int ir = cl + 16 * p;  // local i
    const int cc = il;           // local c
    const f16 h0 = T[cc + 0][ir], h1 = T[cc + 1][ir];
    const f16 h2 = T[cc + 2][ir], h3 = T[cc + 3][ir];
    f16* dF = xf + ((size_t)lb * kN + i0 + ir) * kD + c0 + cc;
    *(f16x4*)dF = (f16x4){h0, h1, h2, h3};
  }
}

// ---- K2: S = kScale * xf @ xf^T (f16 MFMA, 128x128 tile, BK=64) ------------
// Epilogue also emits row partial sums of exp(S) over each wave's 64-col
// half-tile -> rp[lb][jtile*2 + half][row]. No max-sub needed: S <= ~38,
// exp(S) well inside fp32; sums are diag-dominated.
__global__ __launch_bounds__(256) void k_gemm_s(
    const f16* __restrict__ xf, float* __restrict__ S,
    float* __restrict__ rp) {
  __shared__ f16 As[128][LDK];
  __shared__ f16 Bs[128][LDK];
  const int lb = blockIdx.z;
  const int i0 = blockIdx.y * 128, j0 = blockIdx.x * 128;
  const f16* base = xf + (size_t)lb * kN * kD;
  const int t = threadIdx.x;
  const int w = t >> 6, lane = t & 63;
  const int m_off = (w >> 1) * 64, n_off = (w & 1) * 64;
  const int quad = lane >> 4, l15 = lane & 15;
  const int sc = (t & 7) * 8;  // staging col (8 f16 = 16 B)
  const int sr = t >> 3;       // staging row 0..31
  f32x4 acc[4][4];
#pragma unroll
  for (int a = 0; a < 4; a++)
#pragma unroll
    for (int b = 0; b < 4; b++) acc[a][b] = (f32x4){0.f, 0.f, 0.f, 0.f};

  for (int k0 = 0; k0 < kD; k0 += 64) {
    f16x8 a[4], b[4];
#pragma unroll
    for (int p = 0; p < 4; p++) {
      a[p] = *(const f16x8*)(base + (size_t)(i0 + sr + 32 * p) * kD + k0 + sc);
      b[p] = *(const f16x8*)(base + (size_t)(j0 + sr + 32 * p) * kD + k0 + sc);
    }
    __syncthreads();
#pragma unroll
    for (int p = 0; p < 4; p++) {
      *(f16x8*)&As[sr + 32 * p][sc] = a[p];
      *(f16x8*)&Bs[sr + 32 * p][sc] = b[p];
    }
    __syncthreads();
#pragma unroll
    for (int kk = 0; kk < 64; kk += 32) {
      f16x8 af[4], bf[4];
#pragma unroll
      for (int q = 0; q < 4; q++)
        af[q] = *(const f16x8*)&As[m_off + 16 * q + l15][kk + quad * 8];
#pragma unroll
      for (int q = 0; q < 4; q++)
        bf[q] = *(const f16x8*)&Bs[n_off + 16 * q + l15][kk + quad * 8];
#pragma unroll
      for (int qa = 0; qa < 4; qa++)
#pragma unroll
        for (int qb = 0; qb < 4; qb++)
          acc[qa][qb] = __builtin_amdgcn_mfma_f32_16x16x32_f16(
              af[qa], bf[qb], acc[qa][qb], 0, 0, 0);
    }
  }
  float* Sb = S + (size_t)lb * kN * kN;
#pragma unroll
  for (int qa = 0; qa < 4; qa++) {
    const int i = i0 + m_off + 16 * qa + quad * 4;
#pragma unroll
    for (int qb = 0; qb < 4; qb++) {
      const int j = j0 + n_off + 16 * qb + l15;
#pragma unroll
      for (int r = 0; r < 4; r++)
        Sb[(size_t)(i + r) * kN + j] = acc[qa][qb][r] * kScale;
    }
  }
  // row-sum partials of exp(S) over this wave's 64-col half
  const int jt2 = blockIdx.x * 2 + (w & 1);
  float* rpb = rp + ((size_t)lb * 16 + jt2) * kN + i0 + m_off;
#pragma unroll
  for (int qa = 0; qa < 4; qa++)
#pragma unroll
    for (int r = 0; r < 4; r++) {
      float s = 0.f;
#pragma unroll
      for (int qb = 0; qb < 4; qb++) s += __expf(acc[qa][qb][r] * kScale);
      s += __shfl_xor(s, 1);
      s += __shfl_xor(s, 2);
      s += __shfl_xor(s, 4);
      s += __shfl_xor(s, 8);
      if (l15 == 0) rpb[16 * qa + 4 * quad + r] = s;
    }
}

// ---- K3: u[lb,i] = -log(n) - log(sum of 16 row partials) -------------------
__global__ __launch_bounds__(256) void k_u(
    const float* __restrict__ rp, float* __restrict__ u) {
  const int lb = blockIdx.y;
  const int i = blockIdx.x * 256 + threadIdx.x;
  const float* r = rp + (size_t)lb * 16 * kN + i;
  float s = 0.f;
#pragma unroll
  for (int t = 0; t < 16; t++) s += r[(size_t)t * kN];
  u[lb * kN + i] = kLogMarg - __logf(s);
}

// ---- K4: fused colsum + t16 write. t16[i,j] = f16(2^14 exp(S+u_i)); --------
// cp[seg][j] = partial column sums (64 i per seg). Terms <= 1/n, sums <= 1.
__global__ __launch_bounds__(256) void k_cp(
    const float* __restrict__ S, const float* __restrict__ u,
    float* __restrict__ cp, f16* __restrict__ t16) {
  const int lb = blockIdx.z;
  const int seg = blockIdx.y;
  const int j0 = blockIdx.x * 64;
  const int tx = threadIdx.x & 63;
  const int ty = threadIdx.x >> 6;
  const float* Sb = S + (size_t)lb * kN * kN;
  const float* ub = u + lb * kN;
  f16* tb = t16 + (size_t)lb * kN * kN;
  const int ibase = seg * 64 + ty * 16;
  float s = 0.f;
#pragma unroll 4
  for (int r = 0; r < 16; r++) {
    const int i = ibase + r;
    const float e = __expf(Sb[(size_t)i * kN + j0 + tx] + ub[i]);
    tb[(size_t)i * kN + j0 + tx] = (f16)(e * kPScale);
    s += e;
  }
  __shared__ float Ss[4][64];
  Ss[ty][tx] = s;
  __syncthreads();
  if (ty == 0) {
    s += Ss[1][tx] + Ss[2][tx] + Ss[3][tx];
    cp[((size_t)lb * 16 + seg) * kN + j0 + tx] = s;
  }
}

// ---- K5: ev[lb,j] = exp(v_j) = (1/n) / colsum_j ----------------------------
__global__ __launch_bounds__(256) void k_v(
    const float* __restrict__ cp, float* __restrict__ ev) {
  const int lb = blockIdx.y;
  const int j = blockIdx.x * 256 + threadIdx.x;
  const float* c = cp + (size_t)lb * 16 * kN + j;
  float s = 0.f;
#pragma unroll
  for (int r = 0; r < 16; r++) s += c[(size_t)r * kN];
  ev[lb * kN + j] = kMarg / s;
}

// ---- K6: xfT[lb,c,j] *= ev[lb,j]  (in place, f16x8) ------------------------
__global__ __launch_bounds__(256) void k_scale(
    f16* __restrict__ xfT, const float* __restrict__ ev) {
  const int lb = blockIdx.y;
  const int idx = (blockIdx.x * 256 + threadIdx.x) * 8;  // flat over [c][j]
  const int j = idx & (kN - 1);
  const float* evb = ev + lb * kN;
  const float4 e0 = *(const float4*)(evb + j);
  const float4 e1 = *(const float4*)(evb + j + 4);
  f16* p = xfT + (size_t)lb * kD * kN + idx;
  f16x8 h = *(f16x8*)p;
  h[0] = (f16)((float)h[0] * e0.x); h[1] = (f16)((float)h[1] * e0.y);
  h[2] = (f16)((float)h[2] * e0.z); h[3] = (f16)((float)h[3] * e0.w);
  h[4] = (f16)((float)h[4] * e1.x); h[5] = (f16)((float)h[5] * e1.y);
  h[6] = (f16)((float)h[6] * e1.z); h[7] = (f16)((float)h[7] * e1.w);
  *(f16x8*)p = h;
}

// ---- K7: out[b,c,i] = (1/2^14) * sum_j xfT'[c,j] * t16[i,j]  (f16 MFMA) ----
__global__ __launch_bounds__(256) void k_gemm_o(
    const f16* __restrict__ xfT, const f16* __restrict__ P,
    float* __restrict__ out, int b0) {
  __shared__ f16 As[128][LDK];
  __shared__ f16 Bs[128][LDK];
  const int lb = blockIdx.z;
  const int i0 = blockIdx.x * 128, c0 = blockIdx.y * 128;
  const f16* Ab = xfT + (size_t)lb * kD * kN;
  const f16* Bb = P + (size_t)lb * kN * kN;
  const int t = threadIdx.x;
  const int w = t >> 6, lane = t & 63;
  const int m_off = (w >> 1) * 64, n_off = (w & 1) * 64;
  const int quad = lane >> 4, l15 = lane & 15;
  const int sc = (t & 7) * 8;
  const int sr = t >> 3;
  f32x4 acc[4][4];
#pragma unroll
  for (int a = 0; a < 4; a++)
#pragma unroll
    for (int b = 0; b < 4; b++) acc[a][b] = (f32x4){0.f, 0.f, 0.f, 0.f};

  for (int k0 = 0; k0 < kN; k0 += 64) {
    f16x8 a[4], b[4];
#pragma unroll
    for (int p = 0; p < 4; p++) {
      a[p] = *(const f16x8*)(Ab + (size_t)(c0 + sr + 32 * p) * kN + k0 + sc);
      b[p] = *(const f16x8*)(Bb + (size_t)(i0 + sr + 32 * p) * kN + k0 + sc);
    }
    __syncthreads();
#pragma unroll
    for (int p = 0; p < 4; p++) {
      *(f16x8*)&As[sr + 32 * p][sc] = a[p];
      *(f16x8*)&Bs[sr + 32 * p][sc] = b[p];
    }
    __syncthreads();
#pragma unroll
    for (int kk = 0; kk < 64; kk += 32) {
      f16x8 af[4], bf[4];
#pragma unroll
      for (int q = 0; q < 4; q++)
        af[q] = *(const f16x8*)&As[m_off + 16 * q + l15][kk + quad * 8];
#pragma unroll
      for (int q = 0; q < 4; q++)
        bf[q] = *(const f16x8*)&Bs[n_off + 16 * q + l15][kk + quad * 8];
#pragma unroll
      for (int qa = 0; qa < 4; qa++)
#pragma unroll
        for (int qb = 0; qb < 4; qb++)
          acc[qa][qb] = __builtin_amdgcn_mfma_f32_16x16x32_f16(
              af[qa], bf[qb], acc[qa][qb], 0, 0, 0);
    }
  }
  float* ob = out + ((size_t)(b0 + lb) * kD) * kN;
#pragma unroll
  for (int qa = 0; qa < 4; qa++) {
    const int c = c0 + m_off + 16 * qa + quad * 4;
#pragma unroll
    for (int qb = 0; qb < 4; qb++) {
      const int i = i0 + n_off + 16 * qb + l15;
#pragma unroll
      for (int r = 0; r < 4; r++)
        ob[(size_t)(c + r) * kN + i] = acc[qa][qb][r] * kPInv;
    }
  }
}

extern "C" void kernel_launch(void* const* d_in, const int* in_sizes, int n_in,
                              void* d_out, int out_size, void* d_ws, size_t ws_size,
                              hipStream_t stream) {
  const float* x = (const float*)d_in[0];
  const float* re = (const float*)d_in[1];
  const float* ce = (const float*)d_in[2];
  float* out = (float*)d_out;

  // ws per batch: S 4MB + xf 1MB + xfT 1MB + t16 2MB + u 4KB + ev 4KB
  //             + rp 64KB + cp 64KB  = ~8.13 MB. ws=256MiB -> G=16, 2 chunks.
  char* wsb = (char*)d_ws;
  const size_t perb = 4194304ull + 1048576 + 1048576 + 2097152 +
                      4096 + 4096 + 65536 + 65536;
  int G = (int)(ws_size / perb);
  if (G >= 32) G = 32;
  else if (G >= 16) G = 16;
  else if (G >= 8) G = 8;
  else if (G >= 4) G = 4;
  else if (G < 1) G = 1;
  float* S = (float*)wsb;
  f16* xf = (f16*)(wsb + (size_t)G * 4194304);
  f16* xfT = (f16*)((char*)xf + (size_t)G * 1048576);
  f16* t16 = (f16*)((char*)xfT + (size_t)G * 1048576);
  float* u = (float*)((char*)t16 + (size_t)G * 2097152);
  float* ev = u + (size_t)G * kN;
  float* rp = ev + (size_t)G * kN;            // [G][16][kN]
  float* cp = rp + (size_t)G * 16 * kN;       // [G][16][kN]

  for (int b0 = 0; b0 < kB; b0 += G) {
    const int g = (kB - b0 < G) ? (kB - b0) : G;
    k_prep<<<dim3(16, 8, g), 256, 0, stream>>>(x, re, ce, xf, xfT, b0);
    k_gemm_s<<<dim3(8, 8, g), 256, 0, stream>>>(xf, S, rp);
    k_u<<<dim3(4, g), 256, 0, stream>>>(rp, u);
    k_cp<<<dim3(16, 16, g), 256, 0, stream>>>(S, u, cp, t16);
    k_v<<<dim3(4, g), 256, 0, stream>>>(cp, ev);
    k_scale<<<dim3(256, g), 256, 0, stream>>>(xfT, ev);
    k_gemm_o<<<dim3(8, 4, g), 256, 0, stream>>>(xfT, t16, out, b0);
  }
}

// Round 8
// 287.013 us; speedup vs baseline: 5.1090x; 1.0826x over previous
//
#include <hip/hip_runtime.h>
#include <hip/hip_fp16.h>
#include <math.h>

typedef _Float16 f16;
typedef _Float16 f16x8 __attribute__((ext_vector_type(8)));
typedef _Float16 f16x4 __attribute__((ext_vector_type(4)));
typedef float f32x4 __attribute__((ext_vector_type(4)));

namespace {
constexpr int kB = 32, kD = 512, kN = 1024, kF = 256;
constexpr float kScale = 0.04419417382415922f;   // 1/sqrt(512)
constexpr float kLogMarg = -6.931471805599453f;  // -log(1024)
constexpr float kMarg = 1.f / 1024.f;            // 1/n
constexpr float kPScale = 16384.f;               // 2^14: lift t into f16 range
constexpr float kPInv = 1.f / 16384.f;
constexpr int LDK = 72;  // padded LDS row: 72 f16 = 144 B (16B-aligned, 2-way banks)
}

// ---- K1: val = x[b,c,i] + pos(c,i); emit xfT[lb,c,i] and xf[lb,i,c] (f16) --
__global__ __launch_bounds__(256) void k_prep(
    const float* __restrict__ x, const float* __restrict__ re,
    const float* __restrict__ ce, f16* __restrict__ xf,
    f16* __restrict__ xfT, int b0) {
  __shared__ f16 T[64][68];
  const int lb = blockIdx.z;
  const int i0 = blockIdx.x * 64, c0 = blockIdx.y * 64;
  const int t = threadIdx.x;
  const int il = (t & 15) * 4;  // 0..60
  const int cl = t >> 4;        // 0..15
  const size_t xbase = ((size_t)(b0 + lb) * kD) * kN;
#pragma unroll
  for (int p = 0; p < 4; p++) {
    const int c = c0 + cl + 16 * p;
    const int i = i0 + il;
    const float4 xv = *(const float4*)(x + xbase + (size_t)c * kN + i);
    float4 pv;
    if (c < kF) {  // wave-uniform per block (c0 multiple of 64)
      pv.x = ce[((i + 0) & 31) * kF + c];
      pv.y = ce[((i + 1) & 31) * kF + c];
      pv.z = ce[((i + 2) & 31) * kF + c];
      pv.w = ce[((i + 3) & 31) * kF + c];
    } else {
      const float r = re[(i >> 5) * kF + (c - kF)];
      pv.x = r; pv.y = r; pv.z = r; pv.w = r;
    }
    const f16 h0 = (f16)(xv.x + pv.x), h1 = (f16)(xv.y + pv.y);
    const f16 h2 = (f16)(xv.z + pv.z), h3 = (f16)(xv.w + pv.w);
    f16* dT = xfT + ((size_t)lb * kD + c) * kN + i;
    *(f16x4*)dT = (f16x4){h0, h1, h2, h3};
    T[cl + 16 * p][il + 0] = h0; T[cl + 16 * p][il + 1] = h1;
    T[cl + 16 * p][il + 2] = h2; T[cl + 16 * p][il + 3] = h3;
  }
  __syncthreads();
#pragma unroll
  for (int p = 0; p < 4; p++) {
    const int ir = cl + 16 * p;  // local i
    const int cc = il;           // local c
    const f16 h0 = T[cc + 0][ir], h1 = T[cc + 1][ir];
    const f16 h2 = T[cc + 2][ir], h3 = T[cc + 3][ir];
    f16* dF = xf + ((size_t)lb * kN + i0 + ir) * kD + c0 + cc;
    *(f16x4*)dF = (f16x4){h0, h1, h2, h3};
  }
}

// ---- K2: S16 = f16(kScale * xf @ xf^T) (f16 MFMA, 128x128 tile, BK=64) -----
// Row partials of exp(S16) use the ROUNDED value, so u computed from them
// exactly cancels the diagonal's f16 rounding in pi = exp(S16+u+v).
__global__ __launch_bounds__(256) void k_gemm_s(
    const f16* __restrict__ xf, f16* __restrict__ S16,
    float* __restrict__ rp) {
  __shared__ f16 As[128][LDK];
  __shared__ f16 Bs[128][LDK];
  const int lb = blockIdx.z;
  const int i0 = blockIdx.y * 128, j0 = blockIdx.x * 128;
  const f16* base = xf + (size_t)lb * kN * kD;
  const int t = threadIdx.x;
  const int w = t >> 6, lane = t & 63;
  const int m_off = (w >> 1) * 64, n_off = (w & 1) * 64;
  const int quad = lane >> 4, l15 = lane & 15;
  const int sc = (t & 7) * 8;  // staging col (8 f16 = 16 B)
  const int sr = t >> 3;       // staging row 0..31
  f32x4 acc[4][4];
#pragma unroll
  for (int a = 0; a < 4; a++)
#pragma unroll
    for (int b = 0; b < 4; b++) acc[a][b] = (f32x4){0.f, 0.f, 0.f, 0.f};

  for (int k0 = 0; k0 < kD; k0 += 64) {
    f16x8 a[4], b[4];
#pragma unroll
    for (int p = 0; p < 4; p++) {
      a[p] = *(const f16x8*)(base + (size_t)(i0 + sr + 32 * p) * kD + k0 + sc);
      b[p] = *(const f16x8*)(base + (size_t)(j0 + sr + 32 * p) * kD + k0 + sc);
    }
    __syncthreads();
#pragma unroll
    for (int p = 0; p < 4; p++) {
      *(f16x8*)&As[sr + 32 * p][sc] = a[p];
      *(f16x8*)&Bs[sr + 32 * p][sc] = b[p];
    }
    __syncthreads();
#pragma unroll
    for (int kk = 0; kk < 64; kk += 32) {
      f16x8 af[4], bf[4];
#pragma unroll
      for (int q = 0; q < 4; q++)
        af[q] = *(const f16x8*)&As[m_off + 16 * q + l15][kk + quad * 8];
#pragma unroll
      for (int q = 0; q < 4; q++)
        bf[q] = *(const f16x8*)&Bs[n_off + 16 * q + l15][kk + quad * 8];
#pragma unroll
      for (int qa = 0; qa < 4; qa++)
#pragma unroll
        for (int qb = 0; qb < 4; qb++)
          acc[qa][qb] = __builtin_amdgcn_mfma_f32_16x16x32_f16(
              af[qa], bf[qb], acc[qa][qb], 0, 0, 0);
    }
  }
  f16* Sb = S16 + (size_t)lb * kN * kN;
  const int jt2 = blockIdx.x * 2 + (w & 1);
  float* rpb = rp + ((size_t)lb * 16 + jt2) * kN + i0 + m_off;
#pragma unroll
  for (int qa = 0; qa < 4; qa++) {
    const int i = i0 + m_off + 16 * qa + quad * 4;
    float rs[4] = {0.f, 0.f, 0.f, 0.f};
#pragma unroll
    for (int qb = 0; qb < 4; qb++) {
      const int j = j0 + n_off + 16 * qb + l15;
#pragma unroll
      for (int r = 0; r < 4; r++) {
        const f16 h = (f16)(acc[qa][qb][r] * kScale);
        Sb[(size_t)(i + r) * kN + j] = h;
        rs[r] += __expf((float)h);
      }
    }
#pragma unroll
    for (int r = 0; r < 4; r++) {
      float s = rs[r];
      s += __shfl_xor(s, 1);
      s += __shfl_xor(s, 2);
      s += __shfl_xor(s, 4);
      s += __shfl_xor(s, 8);
      if (l15 == 0) rpb[16 * qa + 4 * quad + r] = s;
    }
  }
}

// ---- K3: u[lb,i] = -log(n) - log(sum of 16 row partials) -------------------
__global__ __launch_bounds__(256) void k_u(
    const float* __restrict__ rp, float* __restrict__ u) {
  const int lb = blockIdx.y;
  const int i = blockIdx.x * 256 + threadIdx.x;
  const float* r = rp + (size_t)lb * 16 * kN + i;
  float s = 0.f;
#pragma unroll
  for (int t = 0; t < 16; t++) s += r[(size_t)t * kN];
  u[lb * kN + i] = kLogMarg - __logf(s);
}

// ---- K4: column partial sums of exp(S16 + u_i), 64 rows per seg ------------
__global__ __launch_bounds__(256) void k_cs(
    const f16* __restrict__ S16, const float* __restrict__ u,
    float* __restrict__ cp) {
  const int lb = blockIdx.z;
  const int seg = blockIdx.y;
  const int j = blockIdx.x * 256 + threadIdx.x;
  const f16* Sb = S16 + (size_t)lb * kN * kN + j;
  const float* ub = u + lb * kN + seg * 64;
  const size_t rbase = (size_t)(seg * 64) * kN;
  float s = 0.f;
#pragma unroll 4
  for (int r = 0; r < 64; r++)
    s += __expf((float)Sb[rbase + (size_t)r * kN] + ub[r]);
  cp[((size_t)lb * 16 + seg) * kN + j] = s;
}

// ---- K5: ev[lb,j] = exp(v_j) = (1/n) / colsum_j ----------------------------
__global__ __launch_bounds__(256) void k_v(
    const float* __restrict__ cp, float* __restrict__ ev) {
  const int lb = blockIdx.y;
  const int j = blockIdx.x * 256 + threadIdx.x;
  const float* c = cp + (size_t)lb * 16 * kN + j;
  float s = 0.f;
#pragma unroll
  for (int r = 0; r < 16; r++) s += c[(size_t)r * kN];
  ev[lb * kN + j] = kMarg / s;
}

// ---- K6: t16[i,j] = f16(2^14 * exp(S16 + u_i) * ev_j)  (= 2^14 * pi_ij) ----
__global__ __launch_bounds__(256) void k_pt(
    const f16* __restrict__ S16, const float* __restrict__ u,
    const float* __restrict__ ev, f16* __restrict__ t16) {
  const int row = blockIdx.x;  // lb*kN + i
  const float ui = u[row];
  const f16* Sr = S16 + (size_t)row * kN;
  const float* evb = ev + (size_t)(row >> 10) * kN;
  f16* Tr = t16 + (size_t)row * kN;
  const int j = threadIdx.x * 4;
  const f16x4 s = *(const f16x4*)(Sr + j);
  const float4 e = *(const float4*)(evb + j);
  f16x4 o;
  o[0] = (f16)(__expf((float)s[0] + ui) * e.x * kPScale);
  o[1] = (f16)(__expf((float)s[1] + ui) * e.y * kPScale);
  o[2] = (f16)(__expf((float)s[2] + ui) * e.z * kPScale);
  o[3] = (f16)(__expf((float)s[3] + ui) * e.w * kPScale);
  *(f16x4*)(Tr + j) = o;
}

// ---- K7: out[b,c,i] = (1/2^14) * sum_j xfT[c,j] * t16[i,j]  (f16 MFMA) -----
__global__ __launch_bounds__(256) void k_gemm_o(
    const f16* __restrict__ xfT, const f16* __restrict__ P,
    float* __restrict__ out, int b0) {
  __shared__ f16 As[128][LDK];
  __shared__ f16 Bs[128][LDK];
  const int lb = blockIdx.z;
  const int i0 = blockIdx.x * 128, c0 = blockIdx.y * 128;
  const f16* Ab = xfT + (size_t)lb * kD * kN;
  const f16* Bb = P + (size_t)lb * kN * kN;
  const int t = threadIdx.x;
  const int w = t >> 6, lane = t & 63;
  const int m_off = (w >> 1) * 64, n_off = (w & 1) * 64;
  const int quad = lane >> 4, l15 = lane & 15;
  const int sc = (t & 7) * 8;
  const int sr = t >> 3;
  f32x4 acc[4][4];
#pragma unroll
  for (int a = 0; a < 4; a++)
#pragma unroll
    for (int b = 0; b < 4; b++) acc[a][b] = (f32x4){0.f, 0.f, 0.f, 0.f};

  for (int k0 = 0; k0 < kN; k0 += 64) {
    f16x8 a[4], b[4];
#pragma unroll
    for (int p = 0; p < 4; p++) {
      a[p] = *(const f16x8*)(Ab + (size_t)(c0 + sr + 32 * p) * kN + k0 + sc);
      b[p] = *(const f16x8*)(Bb + (size_t)(i0 + sr + 32 * p) * kN + k0 + sc);
    }
    __syncthreads();
#pragma unroll
    for (int p = 0; p < 4; p++) {
      *(f16x8*)&As[sr + 32 * p][sc] = a[p];
      *(f16x8*)&Bs[sr + 32 * p][sc] = b[p];
    }
    __syncthreads();
#pragma unroll
    for (int kk = 0; kk < 64; kk += 32) {
      f16x8 af[4], bf[4];
#pragma unroll
      for (int q = 0; q < 4; q++)
        af[q] = *(const f16x8*)&As[m_off + 16 * q + l15][kk + quad * 8];
#pragma unroll
      for (int q = 0; q < 4; q++)
        bf[q] = *(const f16x8*)&Bs[n_off + 16 * q + l15][kk + quad * 8];
#pragma unroll
      for (int qa = 0; qa < 4; qa++)
#pragma unroll
        for (int qb = 0; qb < 4; qb++)
          acc[qa][qb] = __builtin_amdgcn_mfma_f32_16x16x32_f16(
              af[qa], bf[qb], acc[qa][qb], 0, 0, 0);
    }
  }
  float* ob = out + ((size_t)(b0 + lb) * kD) * kN;
#pragma unroll
  for (int qa = 0; qa < 4; qa++) {
    const int c = c0 + m_off + 16 * qa + quad * 4;
#pragma unroll
    for (int qb = 0; qb < 4; qb++) {
      const int i = i0 + n_off + 16 * qb + l15;
#pragma unroll
      for (int r = 0; r < 4; r++)
        ob[(size_t)(c + r) * kN + i] = acc[qa][qb][r] * kPInv;
    }
  }
}

extern "C" void kernel_launch(void* const* d_in, const int* in_sizes, int n_in,
                              void* d_out, int out_size, void* d_ws, size_t ws_size,
                              hipStream_t stream) {
  const float* x = (const float*)d_in[0];
  const float* re = (const float*)d_in[1];
  const float* ce = (const float*)d_in[2];
  float* out = (float*)d_out;

  // ws per batch: S16 2MB + xf 1MB + xfT 1MB + t16 2MB + u 4KB + ev 4KB
  //             + rp 64KB + cp 64KB = ~6.13 MB. ws=256MiB -> G=32, ONE chunk.
  char* wsb = (char*)d_ws;
  const size_t perb = 2097152ull + 1048576 + 1048576 + 2097152 +
                      4096 + 4096 + 65536 + 65536;
  int G = (int)(ws_size / perb);
  if (G >= 32) G = 32;
  else if (G >= 16) G = 16;
  else if (G >= 8) G = 8;
  else if (G >= 4) G = 4;
  else if (G < 1) G = 1;
  f16* S16 = (f16*)wsb;
  f16* xf = (f16*)(wsb + (size_t)G * 2097152);
  f16* xfT = (f16*)((char*)xf + (size_t)G * 1048576);
  f16* t16 = (f16*)((char*)xfT + (size_t)G * 1048576);
  float* u = (float*)((char*)t16 + (size_t)G * 2097152);
  float* ev = u + (size_t)G * kN;
  float* rp = ev + (size_t)G * kN;            // [G][16][kN]
  float* cp = rp + (size_t)G * 16 * kN;       // [G][16][kN]

  for (int b0 = 0; b0 < kB; b0 += G) {
    const int g = (kB - b0 < G) ? (kB - b0) : G;
    k_prep<<<dim3(16, 8, g), 256, 0, stream>>>(x, re, ce, xf, xfT, b0);
    k_gemm_s<<<dim3(8, 8, g), 256, 0, stream>>>(xf, S16, rp);
    k_u<<<dim3(4, g), 256, 0, stream>>>(rp, u);
    k_cs<<<dim3(4, 16, g), 256, 0, stream>>>(S16, u, cp);
    k_v<<<dim3(4, g), 256, 0, stream>>>(cp, ev);
    k_pt<<<g * kN, 256, 0, stream>>>(S16, u, ev, t16);
    k_gemm_o<<<dim3(8, 4, g), 256, 0, stream>>>(xfT, t16, out, b0);
  }
}